// Round 1
// baseline (693.969 us; speedup 1.0000x reference)
//
#include <hip/hip_runtime.h>

#define NN 50000
#define NE 600000
#define NG 3
#define D  128
#define NI 4096
#define NBLK 49   // ceil(NN/1024)

// ---------------- CSR build ----------------

__global__ __launch_bounds__(256) void hist_kernel(const int* __restrict__ e0,
    const int* __restrict__ e1, const int* __restrict__ e2, int* __restrict__ deg) {
  int t = blockIdx.x * 256 + threadIdx.x;
  if (t >= NG * NE) return;
  int g = t / NE, e = t - g * NE;
  const int* ei = (g == 0) ? e0 : ((g == 1) ? e1 : e2);
  atomicAdd(&deg[g * NN + ei[NE + e]], 1);   // dst row of edge_index
}

__global__ __launch_bounds__(1024) void scan1_kernel(const int* __restrict__ deg,
    int* __restrict__ rp, int* __restrict__ bsums) {
  __shared__ int s[1024];
  int g = blockIdx.x / NBLK, blk = blockIdx.x % NBLK;
  int tid = threadIdx.x;
  int idx = blk * 1024 + tid;
  int v = (idx < NN) ? deg[g * NN + idx] : 0;
  s[tid] = v;
  __syncthreads();
  for (int off = 1; off < 1024; off <<= 1) {
    int t = 0;
    if (tid >= off) t = s[tid - off];
    __syncthreads();
    s[tid] += t;
    __syncthreads();
  }
  if (idx < NN) rp[g * (NN + 1) + idx] = s[tid] - v;   // exclusive
  if (tid == 1023) bsums[g * 64 + blk] = s[tid];       // block total
}

__global__ void scan2_kernel(int* __restrict__ bsums) {
  int g = blockIdx.x;
  if (threadIdx.x != 0) return;
  int run = 0;
  for (int k = 0; k < NBLK; k++) { int t = bsums[g * 64 + k]; bsums[g * 64 + k] = run; run += t; }
}

__global__ __launch_bounds__(256) void scan3_kernel(const int* __restrict__ deg,
    int* __restrict__ rp, int* __restrict__ cur, float* __restrict__ dinv,
    const int* __restrict__ bsums) {
  int t = blockIdx.x * 256 + threadIdx.x;
  if (t < NG) rp[t * (NN + 1) + NN] = NE;
  if (t >= NG * NN) return;
  int g = t / NN, n = t - g * NN;
  int val = rp[g * (NN + 1) + n] + bsums[g * 64 + (n >> 10)];
  rp[g * (NN + 1) + n] = val;
  cur[g * NN + n] = val;
  dinv[g * NN + n] = rsqrtf((float)deg[g * NN + n] + 1.0f);  // deg incl. self loop
}

__global__ __launch_bounds__(256) void fill_kernel(const int* __restrict__ e0,
    const int* __restrict__ e1, const int* __restrict__ e2,
    int* __restrict__ cur, int* __restrict__ col) {
  int t = blockIdx.x * 256 + threadIdx.x;
  if (t >= NG * NE) return;
  int g = t / NE, e = t - g * NE;
  const int* ei = (g == 0) ? e0 : ((g == 1) ? e1 : e2);
  int src = ei[e], dst = ei[NE + e];
  int slot = atomicAdd(&cur[g * NN + dst], 1);
  col[(size_t)g * NE + slot] = src;
}

// ---------------- fp32 matmul: C[M x 128] = A[M x 128] @ W[128 x 128] ----------------
// 64-row tile, 256 threads, each thread 4 rows x 8 cols, K staged in two 64-chunks.
// LDS = 17.4KB (A) + 33.8KB (W) = 51.2KB.

__global__ __launch_bounds__(256) void mm_kernel(const float* __restrict__ A,
    const float* __restrict__ W, float* __restrict__ C, int M) {
  __shared__ float As[64][68];
  __shared__ float Ws[64][132];
  const int tid = threadIdx.x;
  const int tx = tid & 15, ty = tid >> 4;
  const int row0 = blockIdx.x * 64;
  const int c0 = tx * 8;
  float acc[4][8];
#pragma unroll
  for (int r = 0; r < 4; r++)
#pragma unroll
    for (int c = 0; c < 8; c++) acc[r][c] = 0.f;

  for (int kc = 0; kc < 128; kc += 64) {
    // stage A tile: 64 rows x 64 k
#pragma unroll
    for (int t = 0; t < 4; ++t) {
      int idx = tid + t * 256;      // 0..1023 float4 slots
      int r = idx >> 4;
      int cc = (idx & 15) * 4;
      float4 v = make_float4(0.f, 0.f, 0.f, 0.f);
      int gr = row0 + r;
      if (gr < M) v = *(const float4*)&A[(size_t)gr * 128 + kc + cc];
      *(float4*)&As[r][cc] = v;
    }
    // stage W tile: 64 k x 128 cols
#pragma unroll
    for (int t = 0; t < 8; ++t) {
      int idx = tid + t * 256;      // 0..2047 float4 slots
      int k = idx >> 5;
      int cc = (idx & 31) * 4;
      float4 v = *(const float4*)&W[(size_t)(kc + k) * 128 + cc];
      *(float4*)&Ws[k][cc] = v;
    }
    __syncthreads();
#pragma unroll
    for (int k4 = 0; k4 < 16; ++k4) {
      float4 a4[4];
#pragma unroll
      for (int r = 0; r < 4; r++) a4[r] = *(const float4*)&As[ty + r * 16][k4 * 4];
#pragma unroll
      for (int kk = 0; kk < 4; kk++) {
        float4 w0 = *(const float4*)&Ws[k4 * 4 + kk][c0];
        float4 w1 = *(const float4*)&Ws[k4 * 4 + kk][c0 + 4];
#pragma unroll
        for (int r = 0; r < 4; r++) {
          float a = (&a4[r].x)[kk];
          acc[r][0] += a * w0.x; acc[r][1] += a * w0.y;
          acc[r][2] += a * w0.z; acc[r][3] += a * w0.w;
          acc[r][4] += a * w1.x; acc[r][5] += a * w1.y;
          acc[r][6] += a * w1.z; acc[r][7] += a * w1.w;
        }
      }
    }
    __syncthreads();
  }
#pragma unroll
  for (int r = 0; r < 4; r++) {
    int gr = row0 + ty + r * 16;
    if (gr < M) {
      *(float4*)&C[(size_t)gr * 128 + c0] =
          make_float4(acc[r][0], acc[r][1], acc[r][2], acc[r][3]);
      *(float4*)&C[(size_t)gr * 128 + c0 + 4] =
          make_float4(acc[r][4], acc[r][5], acc[r][6], acc[r][7]);
    }
  }
}

// ---------------- aggregation: one wave per output row ----------------
// out_row = relu( dinv[i]*( dinv[i]*h[i] + sum_e dinv[src]*h[src] ) + bias )
// combined across branches with max (first branch writes, later branches max).

__global__ __launch_bounds__(256) void agg_kernel(
    const float* __restrict__ h, const int* __restrict__ rp,
    const int* __restrict__ col, const float* __restrict__ dinv,
    const float* __restrict__ bias, float* __restrict__ out,
    const int* __restrict__ index, int nrows, int first) {
  int w = (blockIdx.x * 256 + threadIdx.x) >> 6;
  if (w >= nrows) return;
  int lane = threadIdx.x & 63;
  int node = index ? index[w] : w;
  int d0 = lane * 2;
  float di = dinv[node];
  float2 hv = *(const float2*)&h[(size_t)node * 128 + d0];
  float ax = di * hv.x, ay = di * hv.y;
  int start = rp[node], end = rp[node + 1];
  for (int b0 = start; b0 < end; b0 += 64) {
    int n = end - b0; if (n > 64) n = 64;
    int src = (lane < n) ? col[b0 + lane] : 0;
    for (int j = 0; j < n; ++j) {
      int s = __shfl(src, j, 64);
      float ws = dinv[s];
      float2 v = *(const float2*)&h[(size_t)s * 128 + d0];
      ax += ws * v.x; ay += ws * v.y;
    }
  }
  float2 bv = *(const float2*)&bias[d0];
  float rx = fmaxf(di * ax + bv.x, 0.f);
  float ry = fmaxf(di * ay + bv.y, 0.f);
  float2* o = (float2*)&out[(size_t)w * 128 + d0];
  if (first) {
    *o = make_float2(rx, ry);
  } else {
    float2 prev = *o;
    *o = make_float2(fmaxf(prev.x, rx), fmaxf(prev.y, ry));
  }
}

// ---------------- launch ----------------

extern "C" void kernel_launch(void* const* d_in, const int* in_sizes, int n_in,
                              void* d_out, int out_size, void* d_ws, size_t ws_size,
                              hipStream_t stream) {
  const float* x = (const float*)d_in[0];
  const int* e0 = (const int*)d_in[1];
  const int* e1 = (const int*)d_in[2];
  const int* e2 = (const int*)d_in[3];
  const int* index = (const int*)d_in[4];
  // dict order: w1_syn,b1_syn,w2_syn,b2_syn, w1_seq,b1_seq,w2_seq,b2_seq, w1_sem,...
  const float* w1[3] = {(const float*)d_in[5], (const float*)d_in[9],  (const float*)d_in[13]};
  const float* b1[3] = {(const float*)d_in[6], (const float*)d_in[10], (const float*)d_in[14]};
  const float* w2[3] = {(const float*)d_in[7], (const float*)d_in[11], (const float*)d_in[15]};
  const float* b2[3] = {(const float*)d_in[8], (const float*)d_in[12], (const float*)d_in[16]};
  float* out = (float*)d_out;

  char* ws = (char*)d_ws;
  size_t o = 0;
  auto alloc = [&](size_t bytes) {
    o = (o + 255) & ~(size_t)255;
    void* p = ws + o;
    o += bytes;
    return p;
  };
  int*   deg   = (int*)alloc((size_t)NG * NN * 4);
  int*   rp    = (int*)alloc((size_t)NG * (NN + 1) * 4);
  int*   cur   = (int*)alloc((size_t)NG * NN * 4);
  int*   col   = (int*)alloc((size_t)NG * NE * 4);
  float* dinv  = (float*)alloc((size_t)NG * NN * 4);
  int*   bsums = (int*)alloc((size_t)NG * 64 * 4);
  float* htmp  = (float*)alloc((size_t)NN * D * 4);
  float* hacc  = (float*)alloc((size_t)NN * D * 4);
  (void)ws_size; (void)in_sizes; (void)n_in; (void)out_size;

  hipMemsetAsync(deg, 0, (size_t)NG * NN * 4, stream);
  hist_kernel<<<(NG * NE + 255) / 256, 256, 0, stream>>>(e0, e1, e2, deg);
  scan1_kernel<<<NG * NBLK, 1024, 0, stream>>>(deg, rp, bsums);
  scan2_kernel<<<NG, 64, 0, stream>>>(bsums);
  scan3_kernel<<<(NG * NN + 255) / 256, 256, 0, stream>>>(deg, rp, cur, dinv, bsums);
  fill_kernel<<<(NG * NE + 255) / 256, 256, 0, stream>>>(e0, e1, e2, cur, col);

  // layer 1: h = max_b relu(gcn_b(x))  -> hacc
  for (int b = 0; b < 3; b++) {
    mm_kernel<<<(NN + 63) / 64, 256, 0, stream>>>(x, w1[b], htmp, NN);
    agg_kernel<<<(NN * 64 + 255) / 256, 256, 0, stream>>>(
        htmp, rp + b * (NN + 1), col + (size_t)b * NE, dinv + b * NN,
        b1[b], hacc, nullptr, NN, b == 0);
  }
  // layer 2: out = (max_b relu(gcn_b(hacc)))[index]  -> only 4096 rows
  for (int b = 0; b < 3; b++) {
    mm_kernel<<<(NN + 63) / 64, 256, 0, stream>>>(hacc, w2[b], htmp, NN);
    agg_kernel<<<(NI * 64 + 255) / 256, 256, 0, stream>>>(
        htmp, rp + b * (NN + 1), col + (size_t)b * NE, dinv + b * NN,
        b2[b], out, index, NI, b == 0);
  }
}

// Round 2
// 557.972 us; speedup vs baseline: 1.2437x; 1.2437x over previous
//
#include <hip/hip_runtime.h>

#define NN 50000
#define NE 600000
#define NG 3
#define D  128
#define NI 4096
#define BW 1024                         // nodes per bucket
#define NBUCK 49                        // ceil(NN/BW)
#define EPT_BIN 16
#define EPB_BIN (256 * EPT_BIN)         // 4096 edges per block
#define NBLK_BIN ((NE + EPB_BIN - 1) / EPB_BIN)   // 147

// ---------------- CSR build, bucketed (write-amplification-free) ----------------

__global__ __launch_bounds__(256) void count_kernel(const int* __restrict__ e0,
    const int* __restrict__ e1, const int* __restrict__ e2, int* __restrict__ bucketCnt) {
  __shared__ int cnt[NBUCK];
  int g = blockIdx.y;
  const int* ei = (g == 0) ? e0 : ((g == 1) ? e1 : e2);
  int tid = threadIdx.x;
  if (tid < NBUCK) cnt[tid] = 0;
  __syncthreads();
  int base = blockIdx.x * EPB_BIN;
#pragma unroll
  for (int i = 0; i < EPT_BIN; i++) {
    int e = base + tid + i * 256;
    if (e < NE) atomicAdd(&cnt[ei[NE + e] >> 10], 1);
  }
  __syncthreads();
  if (tid < NBUCK) atomicAdd(&bucketCnt[g * NBUCK + tid], cnt[tid]);
}

__global__ void bscan_kernel(const int* __restrict__ bucketCnt, int* __restrict__ bucketBase,
                             int* __restrict__ cursor, int* __restrict__ rp) {
  int g = threadIdx.x;
  if (g >= NG) return;
  int run = 0;
  for (int b = 0; b < NBUCK; b++) {
    int c = bucketCnt[g * NBUCK + b];
    bucketBase[g * NBUCK + b] = run;
    cursor[g * NBUCK + b] = run;
    run += c;
  }
  rp[g * (NN + 1) + NN] = NE;
}

__global__ __launch_bounds__(256) void bin_kernel(const int* __restrict__ e0,
    const int* __restrict__ e1, const int* __restrict__ e2,
    int* __restrict__ cursor, int2* __restrict__ binned) {
  __shared__ int cnt[NBUCK];
  __shared__ int base[NBUCK];
  int g = blockIdx.y;
  const int* ei = (g == 0) ? e0 : ((g == 1) ? e1 : e2);
  int tid = threadIdx.x;
  if (tid < NBUCK) cnt[tid] = 0;
  __syncthreads();
  int estart = blockIdx.x * EPB_BIN;
  int src[EPT_BIN], dst[EPT_BIN], rk[EPT_BIN];
#pragma unroll
  for (int i = 0; i < EPT_BIN; i++) {
    int e = estart + tid + i * 256;
    if (e < NE) {
      src[i] = ei[e];
      dst[i] = ei[NE + e];
      rk[i] = atomicAdd(&cnt[dst[i] >> 10], 1);
    } else {
      rk[i] = -1;
    }
  }
  __syncthreads();
  if (tid < NBUCK) base[tid] = (cnt[tid] > 0) ? atomicAdd(&cursor[g * NBUCK + tid], cnt[tid]) : 0;
  __syncthreads();
#pragma unroll
  for (int i = 0; i < EPT_BIN; i++) {
    if (rk[i] >= 0) {
      int b = dst[i] >> 10;
      binned[(size_t)g * NE + base[b] + rk[i]] = make_int2(src[i], dst[i]);
    }
  }
}

// one block per (graph, bucket): exact CSR within the bucket's private region
__global__ __launch_bounds__(256) void csr_kernel(const int2* __restrict__ binned,
    const int* __restrict__ bucketBase, const int* __restrict__ bucketCnt,
    int* __restrict__ rp, int* __restrict__ col, float* __restrict__ dinv) {
  __shared__ int deg[BW];
  __shared__ int wsum[4];
  int g = blockIdx.y, b = blockIdx.x;
  int tid = threadIdx.x;
  int node0 = b * BW;
  int bb = bucketBase[g * NBUCK + b];
  int total = bucketCnt[g * NBUCK + b];
  const int2* bp = binned + (size_t)g * NE + bb;
  for (int i = tid; i < BW; i += 256) deg[i] = 0;
  __syncthreads();
  for (int e = tid; e < total; e += 256) {
    int2 p = bp[e];
    atomicAdd(&deg[p.y - node0], 1);
  }
  __syncthreads();
  // exclusive scan of deg[0..1023]: 4 elements per thread + wave scan of partials
  int d0 = deg[tid * 4], d1 = deg[tid * 4 + 1], d2 = deg[tid * 4 + 2], d3 = deg[tid * 4 + 3];
  int s = d0 + d1 + d2 + d3;
  int lane = tid & 63;
  int incl = s;
#pragma unroll
  for (int off = 1; off < 64; off <<= 1) {
    int n = __shfl_up(incl, off, 64);
    if (lane >= off) incl += n;
  }
  if (lane == 63) wsum[tid >> 6] = incl;
  __syncthreads();
  int wbase = 0;
#pragma unroll
  for (int w = 0; w < 4; w++)
    if (w < (tid >> 6)) wbase += wsum[w];
  int ex = wbase + incl - s;
  int exs[4] = {ex, ex + d0, ex + d0 + d1, ex + d0 + d1 + d2};
  int ds[4] = {d0, d1, d2, d3};
#pragma unroll
  for (int k = 0; k < 4; k++) {
    int node = node0 + tid * 4 + k;
    if (node < NN) {
      rp[g * (NN + 1) + node] = bb + exs[k];
      dinv[g * NN + node] = rsqrtf((float)ds[k] + 1.0f);   // deg incl. self loop
    }
    deg[tid * 4 + k] = exs[k];   // LDS becomes local cursor
  }
  __syncthreads();
  for (int e = tid; e < total; e += 256) {
    int2 p = bp[e];
    int r = atomicAdd(&deg[p.y - node0], 1);
    col[(size_t)g * NE + bb + r] = p.x;
  }
}

// ---------------- fp32 matmul: C[M x 128] = A[M x 128] @ W[128 x 128] ----------------

__global__ __launch_bounds__(256) void mm_kernel(const float* __restrict__ A,
    const float* __restrict__ W, float* __restrict__ C, int M) {
  __shared__ float As[64][68];
  __shared__ float Ws[64][132];
  const int tid = threadIdx.x;
  const int tx = tid & 15, ty = tid >> 4;
  const int row0 = blockIdx.x * 64;
  const int c0 = tx * 8;
  float acc[4][8];
#pragma unroll
  for (int r = 0; r < 4; r++)
#pragma unroll
    for (int c = 0; c < 8; c++) acc[r][c] = 0.f;

  for (int kc = 0; kc < 128; kc += 64) {
#pragma unroll
    for (int t = 0; t < 4; ++t) {
      int idx = tid + t * 256;
      int r = idx >> 4;
      int cc = (idx & 15) * 4;
      float4 v = make_float4(0.f, 0.f, 0.f, 0.f);
      int gr = row0 + r;
      if (gr < M) v = *(const float4*)&A[(size_t)gr * 128 + kc + cc];
      *(float4*)&As[r][cc] = v;
    }
#pragma unroll
    for (int t = 0; t < 8; ++t) {
      int idx = tid + t * 256;
      int k = idx >> 5;
      int cc = (idx & 31) * 4;
      float4 v = *(const float4*)&W[(size_t)(kc + k) * 128 + cc];
      *(float4*)&Ws[k][cc] = v;
    }
    __syncthreads();
#pragma unroll
    for (int k4 = 0; k4 < 16; ++k4) {
      float4 a4[4];
#pragma unroll
      for (int r = 0; r < 4; r++) a4[r] = *(const float4*)&As[ty + r * 16][k4 * 4];
#pragma unroll
      for (int kk = 0; kk < 4; kk++) {
        float4 w0 = *(const float4*)&Ws[k4 * 4 + kk][c0];
        float4 w1 = *(const float4*)&Ws[k4 * 4 + kk][c0 + 4];
#pragma unroll
        for (int r = 0; r < 4; r++) {
          float a = (&a4[r].x)[kk];
          acc[r][0] += a * w0.x; acc[r][1] += a * w0.y;
          acc[r][2] += a * w0.z; acc[r][3] += a * w0.w;
          acc[r][4] += a * w1.x; acc[r][5] += a * w1.y;
          acc[r][6] += a * w1.z; acc[r][7] += a * w1.w;
        }
      }
    }
    __syncthreads();
  }
#pragma unroll
  for (int r = 0; r < 4; r++) {
    int gr = row0 + ty + r * 16;
    if (gr < M) {
      *(float4*)&C[(size_t)gr * 128 + c0] =
          make_float4(acc[r][0], acc[r][1], acc[r][2], acc[r][3]);
      *(float4*)&C[(size_t)gr * 128 + c0 + 4] =
          make_float4(acc[r][4], acc[r][5], acc[r][6], acc[r][7]);
    }
  }
}

// ---------------- aggregation: one wave per output row ----------------

__global__ __launch_bounds__(256) void agg_kernel(
    const float* __restrict__ h, const int* __restrict__ rp,
    const int* __restrict__ col, const float* __restrict__ dinv,
    const float* __restrict__ bias, float* __restrict__ out,
    const int* __restrict__ index, int nrows, int first) {
  int w = (blockIdx.x * 256 + threadIdx.x) >> 6;
  if (w >= nrows) return;
  int lane = threadIdx.x & 63;
  int node = index ? index[w] : w;
  int d0 = lane * 2;
  float di = dinv[node];
  float2 hv = *(const float2*)&h[(size_t)node * 128 + d0];
  float ax = di * hv.x, ay = di * hv.y;
  int start = rp[node], end = rp[node + 1];
  for (int b0 = start; b0 < end; b0 += 64) {
    int n = end - b0; if (n > 64) n = 64;
    int src = (lane < n) ? col[b0 + lane] : 0;
    for (int j = 0; j < n; ++j) {
      int s = __shfl(src, j, 64);
      float ws = dinv[s];
      float2 v = *(const float2*)&h[(size_t)s * 128 + d0];
      ax += ws * v.x; ay += ws * v.y;
    }
  }
  float2 bv = *(const float2*)&bias[d0];
  float rx = fmaxf(di * ax + bv.x, 0.f);
  float ry = fmaxf(di * ay + bv.y, 0.f);
  float2* o = (float2*)&out[(size_t)w * 128 + d0];
  if (first) {
    *o = make_float2(rx, ry);
  } else {
    float2 prev = *o;
    *o = make_float2(fmaxf(prev.x, rx), fmaxf(prev.y, ry));
  }
}

// ---------------- launch ----------------

extern "C" void kernel_launch(void* const* d_in, const int* in_sizes, int n_in,
                              void* d_out, int out_size, void* d_ws, size_t ws_size,
                              hipStream_t stream) {
  const float* x = (const float*)d_in[0];
  const int* e0 = (const int*)d_in[1];
  const int* e1 = (const int*)d_in[2];
  const int* e2 = (const int*)d_in[3];
  const int* index = (const int*)d_in[4];
  const float* w1[3] = {(const float*)d_in[5], (const float*)d_in[9],  (const float*)d_in[13]};
  const float* b1[3] = {(const float*)d_in[6], (const float*)d_in[10], (const float*)d_in[14]};
  const float* w2[3] = {(const float*)d_in[7], (const float*)d_in[11], (const float*)d_in[15]};
  const float* b2[3] = {(const float*)d_in[8], (const float*)d_in[12], (const float*)d_in[16]};
  float* out = (float*)d_out;

  char* ws = (char*)d_ws;
  size_t o = 0;
  auto alloc = [&](size_t bytes) {
    o = (o + 255) & ~(size_t)255;
    void* p = ws + o;
    o += bytes;
    return p;
  };
  int*   rp     = (int*)alloc((size_t)NG * (NN + 1) * 4);
  int*   col    = (int*)alloc((size_t)NG * NE * 4);
  float* dinv   = (float*)alloc((size_t)NG * NN * 4);
  int*   bcnt   = (int*)alloc((size_t)NG * NBUCK * 4);
  int*   bbase  = (int*)alloc((size_t)NG * NBUCK * 4);
  int*   bcur   = (int*)alloc((size_t)NG * NBUCK * 4);
  float* htmp   = (float*)alloc((size_t)NN * D * 4);
  float* hacc   = (float*)alloc((size_t)NN * D * 4);
  int2*  binned = (int2*)hacc;   // alias: binned consumed by csr_kernel before agg writes hacc
  (void)ws_size; (void)in_sizes; (void)n_in; (void)out_size;

  hipMemsetAsync(bcnt, 0, (size_t)NG * NBUCK * 4, stream);
  count_kernel<<<dim3(NBLK_BIN, NG), 256, 0, stream>>>(e0, e1, e2, bcnt);
  bscan_kernel<<<1, 64, 0, stream>>>(bcnt, bbase, bcur, rp);
  bin_kernel<<<dim3(NBLK_BIN, NG), 256, 0, stream>>>(e0, e1, e2, bcur, binned);
  csr_kernel<<<dim3(NBUCK, NG), 256, 0, stream>>>(binned, bbase, bcnt, rp, col, dinv);

  // layer 1: hacc = max_b relu(gcn_b(x))
  for (int b = 0; b < 3; b++) {
    mm_kernel<<<(NN + 63) / 64, 256, 0, stream>>>(x, w1[b], htmp, NN);
    agg_kernel<<<(NN * 64 + 255) / 256, 256, 0, stream>>>(
        htmp, rp + b * (NN + 1), col + (size_t)b * NE, dinv + b * NN,
        b1[b], hacc, nullptr, NN, b == 0);
  }
  // layer 2: out = (max_b relu(gcn_b(hacc)))[index]  -> only 4096 rows
  for (int b = 0; b < 3; b++) {
    mm_kernel<<<(NN + 63) / 64, 256, 0, stream>>>(hacc, w2[b], htmp, NN);
    agg_kernel<<<(NI * 64 + 255) / 256, 256, 0, stream>>>(
        htmp, rp + b * (NN + 1), col + (size_t)b * NE, dinv + b * NN,
        b2[b], out, index, NI, b == 0);
  }
}

// Round 3
// 464.114 us; speedup vs baseline: 1.4953x; 1.2022x over previous
//
#include <hip/hip_runtime.h>

#define NN 50000
#define NE 600000
#define NG 3
#define D  128
#define NI 4096
#define BW 1024                         // nodes per bucket
#define NBUCK 49                        // ceil(NN/BW)
#define EPT_BIN 16
#define EPB_BIN (256 * EPT_BIN)         // 4096 edges per block
#define NBLK_BIN ((NE + EPB_BIN - 1) / EPB_BIN)   // 147

// ---------------- CSR build, bucketed (write-amplification-free) ----------------

__global__ __launch_bounds__(256) void count_kernel(const int* __restrict__ e0,
    const int* __restrict__ e1, const int* __restrict__ e2, int* __restrict__ bucketCnt) {
  __shared__ int cnt[NBUCK];
  int g = blockIdx.y;
  const int* ei = (g == 0) ? e0 : ((g == 1) ? e1 : e2);
  int tid = threadIdx.x;
  if (tid < NBUCK) cnt[tid] = 0;
  __syncthreads();
  int base = blockIdx.x * EPB_BIN;
#pragma unroll
  for (int i = 0; i < EPT_BIN; i++) {
    int e = base + tid + i * 256;
    if (e < NE) atomicAdd(&cnt[ei[NE + e] >> 10], 1);
  }
  __syncthreads();
  if (tid < NBUCK) atomicAdd(&bucketCnt[g * NBUCK + tid], cnt[tid]);
}

__global__ void bscan_kernel(const int* __restrict__ bucketCnt, int* __restrict__ bucketBase,
                             int* __restrict__ cursor, int* __restrict__ rp) {
  int g = threadIdx.x;
  if (g >= NG) return;
  int run = 0;
  for (int b = 0; b < NBUCK; b++) {
    int c = bucketCnt[g * NBUCK + b];
    bucketBase[g * NBUCK + b] = run;
    cursor[g * NBUCK + b] = run;
    run += c;
  }
  rp[g * (NN + 1) + NN] = NE;
}

__global__ __launch_bounds__(256) void bin_kernel(const int* __restrict__ e0,
    const int* __restrict__ e1, const int* __restrict__ e2,
    int* __restrict__ cursor, int2* __restrict__ binned) {
  __shared__ int cnt[NBUCK];
  __shared__ int base[NBUCK];
  int g = blockIdx.y;
  const int* ei = (g == 0) ? e0 : ((g == 1) ? e1 : e2);
  int tid = threadIdx.x;
  if (tid < NBUCK) cnt[tid] = 0;
  __syncthreads();
  int estart = blockIdx.x * EPB_BIN;
  int src[EPT_BIN], dst[EPT_BIN], rk[EPT_BIN];
#pragma unroll
  for (int i = 0; i < EPT_BIN; i++) {
    int e = estart + tid + i * 256;
    if (e < NE) {
      src[i] = ei[e];
      dst[i] = ei[NE + e];
      rk[i] = atomicAdd(&cnt[dst[i] >> 10], 1);
    } else {
      rk[i] = -1;
    }
  }
  __syncthreads();
  if (tid < NBUCK) base[tid] = (cnt[tid] > 0) ? atomicAdd(&cursor[g * NBUCK + tid], cnt[tid]) : 0;
  __syncthreads();
#pragma unroll
  for (int i = 0; i < EPT_BIN; i++) {
    if (rk[i] >= 0) {
      int b = dst[i] >> 10;
      binned[(size_t)g * NE + base[b] + rk[i]] = make_int2(src[i], dst[i]);
    }
  }
}

__global__ __launch_bounds__(256) void csr_kernel(const int2* __restrict__ binned,
    const int* __restrict__ bucketBase, const int* __restrict__ bucketCnt,
    int* __restrict__ rp, int* __restrict__ col, float* __restrict__ dinv) {
  __shared__ int deg[BW];
  __shared__ int wsum[4];
  int g = blockIdx.y, b = blockIdx.x;
  int tid = threadIdx.x;
  int node0 = b * BW;
  int bb = bucketBase[g * NBUCK + b];
  int total = bucketCnt[g * NBUCK + b];
  const int2* bp = binned + (size_t)g * NE + bb;
  for (int i = tid; i < BW; i += 256) deg[i] = 0;
  __syncthreads();
  for (int e = tid; e < total; e += 256) {
    int2 p = bp[e];
    atomicAdd(&deg[p.y - node0], 1);
  }
  __syncthreads();
  int d0 = deg[tid * 4], d1 = deg[tid * 4 + 1], d2 = deg[tid * 4 + 2], d3 = deg[tid * 4 + 3];
  int s = d0 + d1 + d2 + d3;
  int lane = tid & 63;
  int incl = s;
#pragma unroll
  for (int off = 1; off < 64; off <<= 1) {
    int n = __shfl_up(incl, off, 64);
    if (lane >= off) incl += n;
  }
  if (lane == 63) wsum[tid >> 6] = incl;
  __syncthreads();
  int wbase = 0;
#pragma unroll
  for (int w = 0; w < 4; w++)
    if (w < (tid >> 6)) wbase += wsum[w];
  int ex = wbase + incl - s;
  int exs[4] = {ex, ex + d0, ex + d0 + d1, ex + d0 + d1 + d2};
  int ds[4] = {d0, d1, d2, d3};
#pragma unroll
  for (int k = 0; k < 4; k++) {
    int node = node0 + tid * 4 + k;
    if (node < NN) {
      rp[g * (NN + 1) + node] = bb + exs[k];
      dinv[g * NN + node] = rsqrtf((float)ds[k] + 1.0f);
    }
    deg[tid * 4 + k] = exs[k];
  }
  __syncthreads();
  for (int e = tid; e < total; e += 256) {
    int2 p = bp[e];
    int r = atomicAdd(&deg[p.y - node0], 1);
    col[(size_t)g * NE + bb + r] = p.x;
  }
}

// ---------------- fp32 matmul: C[M x 128] = (A[M x 128] @ W[128 x 128]) * rowscale ----------------

__global__ __launch_bounds__(256) void mm_kernel(const float* __restrict__ A,
    const float* __restrict__ W, float* __restrict__ C, int M,
    const float* __restrict__ rowscale) {
  __shared__ float As[64][68];
  __shared__ float Ws[64][132];
  const int tid = threadIdx.x;
  const int tx = tid & 15, ty = tid >> 4;
  const int row0 = blockIdx.x * 64;
  const int c0 = tx * 8;
  float acc[4][8];
#pragma unroll
  for (int r = 0; r < 4; r++)
#pragma unroll
    for (int c = 0; c < 8; c++) acc[r][c] = 0.f;

  for (int kc = 0; kc < 128; kc += 64) {
#pragma unroll
    for (int t = 0; t < 4; ++t) {
      int idx = tid + t * 256;
      int r = idx >> 4;
      int cc = (idx & 15) * 4;
      float4 v = make_float4(0.f, 0.f, 0.f, 0.f);
      int gr = row0 + r;
      if (gr < M) v = *(const float4*)&A[(size_t)gr * 128 + kc + cc];
      *(float4*)&As[r][cc] = v;
    }
#pragma unroll
    for (int t = 0; t < 8; ++t) {
      int idx = tid + t * 256;
      int k = idx >> 5;
      int cc = (idx & 31) * 4;
      float4 v = *(const float4*)&W[(size_t)(kc + k) * 128 + cc];
      *(float4*)&Ws[k][cc] = v;
    }
    __syncthreads();
#pragma unroll
    for (int k4 = 0; k4 < 16; ++k4) {
      float4 a4[4];
#pragma unroll
      for (int r = 0; r < 4; r++) a4[r] = *(const float4*)&As[ty + r * 16][k4 * 4];
#pragma unroll
      for (int kk = 0; kk < 4; kk++) {
        float4 w0 = *(const float4*)&Ws[k4 * 4 + kk][c0];
        float4 w1 = *(const float4*)&Ws[k4 * 4 + kk][c0 + 4];
#pragma unroll
        for (int r = 0; r < 4; r++) {
          float a = (&a4[r].x)[kk];
          acc[r][0] += a * w0.x; acc[r][1] += a * w0.y;
          acc[r][2] += a * w0.z; acc[r][3] += a * w0.w;
          acc[r][4] += a * w1.x; acc[r][5] += a * w1.y;
          acc[r][6] += a * w1.z; acc[r][7] += a * w1.w;
        }
      }
    }
    __syncthreads();
  }
#pragma unroll
  for (int r = 0; r < 4; r++) {
    int gr = row0 + ty + r * 16;
    if (gr < M) {
      float sc = rowscale ? rowscale[gr] : 1.0f;
      *(float4*)&C[(size_t)gr * 128 + c0] =
          make_float4(acc[r][0] * sc, acc[r][1] * sc, acc[r][2] * sc, acc[r][3] * sc);
      *(float4*)&C[(size_t)gr * 128 + c0 + 4] =
          make_float4(acc[r][4] * sc, acc[r][5] * sc, acc[r][6] * sc, acc[r][7] * sc);
    }
  }
}

// ---------------- layer-1 aggregation: hs rows are prescaled by dinv ----------------
// out_row = relu( dinv[i]*( hs[i] + sum_e hs[src] ) + bias ); max-combined into hacc.

__global__ __launch_bounds__(256) void agg1_kernel(
    const float* __restrict__ hs, const int* __restrict__ rp,
    const int* __restrict__ col, const float* __restrict__ dinv,
    const float* __restrict__ bias, float* __restrict__ out, int first) {
  int w = (blockIdx.x * 256 + threadIdx.x) >> 6;
  if (w >= NN) return;
  int lane = threadIdx.x & 63;
  int d0 = lane * 2;
  float2 self = *(const float2*)&hs[(size_t)w * D + d0];
  float ax = self.x, ay = self.y;
  int start = rp[w], end = rp[w + 1];
  for (int b0 = start; b0 < end; b0 += 64) {
    int n = end - b0; if (n > 64) n = 64;
    int src = (lane < n) ? col[b0 + lane] : 0;
    int j = 0;
    for (; j + 8 <= n; j += 8) {
      float2 v[8];
#pragma unroll
      for (int k = 0; k < 8; k++) {
        int s = __shfl(src, j + k, 64);
        v[k] = *(const float2*)&hs[(size_t)s * D + d0];
      }
#pragma unroll
      for (int k = 0; k < 8; k++) { ax += v[k].x; ay += v[k].y; }
    }
    for (; j < n; j++) {
      int s = __shfl(src, j, 64);
      float2 v = *(const float2*)&hs[(size_t)s * D + d0];
      ax += v.x; ay += v.y;
    }
  }
  float di = dinv[w];
  float rx = fmaxf(di * ax + bias[d0], 0.f);
  float ry = fmaxf(di * ay + bias[d0 + 1], 0.f);
  float2* o = (float2*)&out[(size_t)w * D + d0];
  if (first) {
    *o = make_float2(rx, ry);
  } else {
    float2 prev = *o;
    *o = make_float2(fmaxf(prev.x, rx), fmaxf(prev.y, ry));
  }
}

// ---------------- layer-2 aggregation (4096 rows of Norm_g(hacc), unscaled input) ----------------
// t[w] = dinv[i]*( dinv[i]*hacc[i] + sum_e dinv[src]*hacc[src] ),  i = index[w]

__global__ __launch_bounds__(256) void agg2_kernel(
    const float* __restrict__ h, const int* __restrict__ rp,
    const int* __restrict__ col, const float* __restrict__ dinv,
    const int* __restrict__ index, float* __restrict__ t) {
  int w = (blockIdx.x * 256 + threadIdx.x) >> 6;
  if (w >= NI) return;
  int lane = threadIdx.x & 63;
  int node = index[w];
  int d0 = lane * 2;
  float di = dinv[node];
  float2 hv = *(const float2*)&h[(size_t)node * D + d0];
  float ax = di * hv.x, ay = di * hv.y;
  int start = rp[node], end = rp[node + 1];
  for (int b0 = start; b0 < end; b0 += 64) {
    int n = end - b0; if (n > 64) n = 64;
    int src = (lane < n) ? col[b0 + lane] : 0;
    int j = 0;
    for (; j + 4 <= n; j += 4) {
      float ws[4]; float2 v[4];
#pragma unroll
      for (int k = 0; k < 4; k++) {
        int s = __shfl(src, j + k, 64);
        ws[k] = dinv[s];
        v[k] = *(const float2*)&h[(size_t)s * D + d0];
      }
#pragma unroll
      for (int k = 0; k < 4; k++) { ax += ws[k] * v[k].x; ay += ws[k] * v[k].y; }
    }
    for (; j < n; j++) {
      int s = __shfl(src, j, 64);
      float wsv = dinv[s];
      float2 v = *(const float2*)&h[(size_t)s * D + d0];
      ax += wsv * v.x; ay += wsv * v.y;
    }
  }
  float2* o = (float2*)&t[(size_t)w * D + d0];
  *o = make_float2(di * ax, di * ay);
}

// ---------------- layer-2 matmul: out = max(out, relu(T @ W + bias)), M = 4096 ----------------

__global__ __launch_bounds__(256) void mmout_kernel(const float* __restrict__ A,
    const float* __restrict__ W, const float* __restrict__ bias,
    float* __restrict__ out, int first) {
  __shared__ float As[64][68];
  __shared__ float Ws[64][132];
  const int tid = threadIdx.x;
  const int tx = tid & 15, ty = tid >> 4;
  const int row0 = blockIdx.x * 64;
  const int c0 = tx * 8;
  float acc[4][8];
#pragma unroll
  for (int r = 0; r < 4; r++)
#pragma unroll
    for (int c = 0; c < 8; c++) acc[r][c] = 0.f;

  for (int kc = 0; kc < 128; kc += 64) {
#pragma unroll
    for (int t = 0; t < 4; ++t) {
      int idx = tid + t * 256;
      int r = idx >> 4;
      int cc = (idx & 15) * 4;
      float4 v = *(const float4*)&A[(size_t)(row0 + r) * 128 + kc + cc];
      *(float4*)&As[r][cc] = v;
    }
#pragma unroll
    for (int t = 0; t < 8; ++t) {
      int idx = tid + t * 256;
      int k = idx >> 5;
      int cc = (idx & 31) * 4;
      float4 v = *(const float4*)&W[(size_t)(kc + k) * 128 + cc];
      *(float4*)&Ws[k][cc] = v;
    }
    __syncthreads();
#pragma unroll
    for (int k4 = 0; k4 < 16; ++k4) {
      float4 a4[4];
#pragma unroll
      for (int r = 0; r < 4; r++) a4[r] = *(const float4*)&As[ty + r * 16][k4 * 4];
#pragma unroll
      for (int kk = 0; kk < 4; kk++) {
        float4 w0 = *(const float4*)&Ws[k4 * 4 + kk][c0];
        float4 w1 = *(const float4*)&Ws[k4 * 4 + kk][c0 + 4];
#pragma unroll
        for (int r = 0; r < 4; r++) {
          float a = (&a4[r].x)[kk];
          acc[r][0] += a * w0.x; acc[r][1] += a * w0.y;
          acc[r][2] += a * w0.z; acc[r][3] += a * w0.w;
          acc[r][4] += a * w1.x; acc[r][5] += a * w1.y;
          acc[r][6] += a * w1.z; acc[r][7] += a * w1.w;
        }
      }
    }
    __syncthreads();
  }
#pragma unroll
  for (int r = 0; r < 4; r++) {
    int gr = row0 + ty + r * 16;
    float4 o0 = make_float4(fmaxf(acc[r][0] + bias[c0], 0.f),
                            fmaxf(acc[r][1] + bias[c0 + 1], 0.f),
                            fmaxf(acc[r][2] + bias[c0 + 2], 0.f),
                            fmaxf(acc[r][3] + bias[c0 + 3], 0.f));
    float4 o1 = make_float4(fmaxf(acc[r][4] + bias[c0 + 4], 0.f),
                            fmaxf(acc[r][5] + bias[c0 + 5], 0.f),
                            fmaxf(acc[r][6] + bias[c0 + 6], 0.f),
                            fmaxf(acc[r][7] + bias[c0 + 7], 0.f));
    float4* p0 = (float4*)&out[(size_t)gr * 128 + c0];
    float4* p1 = (float4*)&out[(size_t)gr * 128 + c0 + 4];
    if (!first) {
      float4 e0 = *p0, e1 = *p1;
      o0 = make_float4(fmaxf(o0.x, e0.x), fmaxf(o0.y, e0.y), fmaxf(o0.z, e0.z), fmaxf(o0.w, e0.w));
      o1 = make_float4(fmaxf(o1.x, e1.x), fmaxf(o1.y, e1.y), fmaxf(o1.z, e1.z), fmaxf(o1.w, e1.w));
    }
    *p0 = o0;
    *p1 = o1;
  }
}

// ---------------- launch ----------------

extern "C" void kernel_launch(void* const* d_in, const int* in_sizes, int n_in,
                              void* d_out, int out_size, void* d_ws, size_t ws_size,
                              hipStream_t stream) {
  const float* x = (const float*)d_in[0];
  const int* e0 = (const int*)d_in[1];
  const int* e1 = (const int*)d_in[2];
  const int* e2 = (const int*)d_in[3];
  const int* index = (const int*)d_in[4];
  const float* w1[3] = {(const float*)d_in[5], (const float*)d_in[9],  (const float*)d_in[13]};
  const float* b1[3] = {(const float*)d_in[6], (const float*)d_in[10], (const float*)d_in[14]};
  const float* w2[3] = {(const float*)d_in[7], (const float*)d_in[11], (const float*)d_in[15]};
  const float* b2[3] = {(const float*)d_in[8], (const float*)d_in[12], (const float*)d_in[16]};
  float* out = (float*)d_out;

  char* ws = (char*)d_ws;
  size_t o = 0;
  auto alloc = [&](size_t bytes) {
    o = (o + 255) & ~(size_t)255;
    void* p = ws + o;
    o += bytes;
    return p;
  };
  int*   rp     = (int*)alloc((size_t)NG * (NN + 1) * 4);
  int*   col    = (int*)alloc((size_t)NG * NE * 4);
  float* dinv   = (float*)alloc((size_t)NG * NN * 4);
  int*   bcnt   = (int*)alloc((size_t)NG * NBUCK * 4);
  int*   bbase  = (int*)alloc((size_t)NG * NBUCK * 4);
  int*   bcur   = (int*)alloc((size_t)NG * NBUCK * 4);
  float* htmp   = (float*)alloc((size_t)NN * D * 4);
  float* hacc   = (float*)alloc((size_t)NN * D * 4);
  int2*  binned = (int2*)hacc;   // alias: consumed by csr_kernel before agg1 writes hacc
  float* t2     = htmp;          // alias: htmp free during layer 2
  (void)ws_size; (void)in_sizes; (void)n_in; (void)out_size;

  hipMemsetAsync(bcnt, 0, (size_t)NG * NBUCK * 4, stream);
  count_kernel<<<dim3(NBLK_BIN, NG), 256, 0, stream>>>(e0, e1, e2, bcnt);
  bscan_kernel<<<1, 64, 0, stream>>>(bcnt, bbase, bcur, rp);
  bin_kernel<<<dim3(NBLK_BIN, NG), 256, 0, stream>>>(e0, e1, e2, bcur, binned);
  csr_kernel<<<dim3(NBUCK, NG), 256, 0, stream>>>(binned, bbase, bcnt, rp, col, dinv);

  // layer 1: hacc = max_b relu( dinv_b ∘ Â_b (x @ W1_b) + b1_b ), rows of htmp prescaled by dinv
  for (int b = 0; b < 3; b++) {
    mm_kernel<<<(NN + 63) / 64, 256, 0, stream>>>(x, w1[b], htmp, NN, dinv + b * NN);
    agg1_kernel<<<(NN * 64 + 255) / 256, 256, 0, stream>>>(
        htmp, rp + b * (NN + 1), col + (size_t)b * NE, dinv + b * NN,
        b1[b], hacc, b == 0);
  }
  // layer 2 (reordered): t = (Norm_b hacc)[index] ; out = max_b relu(t @ W2_b + b2_b)
  for (int b = 0; b < 3; b++) {
    agg2_kernel<<<(NI * 64 + 255) / 256, 256, 0, stream>>>(
        hacc, rp + b * (NN + 1), col + (size_t)b * NE, dinv + b * NN, index, t2);
    mmout_kernel<<<NI / 64, 256, 0, stream>>>(t2, w2[b], b2[b], out, b == 0);
  }
}